// Round 11
// baseline (495.405 us; speedup 1.0000x reference)
//
#include <hip/hip_runtime.h>
#include <hip/hip_fp16.h>
#include <math.h>

typedef _Float16 f16;
typedef _Float16 f16x8 __attribute__((ext_vector_type(8)));
typedef float f32x4 __attribute__((ext_vector_type(4)));
typedef float f32x16 __attribute__((ext_vector_type(16)));
typedef unsigned int u32;
typedef unsigned int u32x4 __attribute__((ext_vector_type(4)));

#define BB 8
#define SS 2048
#define DD 256
#define HH 4
#define DHH 64

#define LOG2E 1.44269504088896340736f
#define MOFF2 (4.0f * LOG2E)          // softmax offset (log2 domain)
#define QSCALE (0.125f * LOG2E)       // 1/sqrt(DH) * log2e, folded into Q store

static __device__ __forceinline__ u32 pkrtz(float a, float b) {
  auto t = __builtin_amdgcn_cvt_pkrtz(a, b);  // __fp16 ext_vector_type(2)
  return __builtin_bit_cast(u32, t);
}

// Manual grid barrier. LEGAL because co-residency is guaranteed by
// construction: 64 KB LDS/block -> max 2 blocks/CU; grid 512 = 2 x 256 CU ->
// all blocks resident before any spins. Release fence BEFORE (L2 writeback,
// per-XCD L2s non-coherent, G16), acquire fence AFTER (invalidate L1/L2
// before reading remote writes) -- round 10's coop version lacked the
// acquire side. Counters zeroed per-launch by a capturable hipMemsetAsync.
static __device__ __forceinline__ void gsync(unsigned* cnt, unsigned target) {
  __threadfence();                     // release
  __syncthreads();
  if (threadIdx.x == 0) {
    atomicAdd(cnt, 1u);                // device-scope by default [m20]
    while (atomicAdd(cnt, 0u) < target) __builtin_amdgcn_s_sleep(8);
  }
  __syncthreads();
  __threadfence();                     // acquire
}

// ---------------------------------------------------------------------------
// ONE kernel, 4 phases with manual grid barriers. Grid 512 x 256.
// Rationale: rounds 0-9 show total = attn + ~100us INVARIANT under major GEMM
// rewrites (round 7 overhaul: -0.4us) => the ~100us is pipeline overhead of
// the 4-launch chain, not kernel time. Fuse 4 launches -> 1 (+1 tiny memset).
// Round 10's hipLaunchCooperativeKernel produced zero output (launch never
// ran -- coop launch is not graph-capture-safe); manual barrier avoids the
// API entirely.
// P2 attn = round-4 structure verbatim (50.2us proven). LDS: one 64 KB
// block, phase-aliased; P1's epilogue transpose reuses the A-stage region
// (dead after A-frags move to regs -- barrier-safe: every wave's a[] ds_reads
// complete before it passes barrier A of iteration i0).
// NO min-waves bound (rounds 5/8: min_waves>=4 collapses to 64 VGPR + spills).
// Plain loads + ds_write only. permlane builtin only (rounds 2/3 hazard).
// ---------------------------------------------------------------------------
__global__ __launch_bounds__(256) void fused_kernel(
    const float* __restrict__ x, const float* __restrict__ wq,
    const float* __restrict__ wk, const float* __restrict__ wv,
    const float* __restrict__ wo, const float* __restrict__ bo,
    f16* __restrict__ wqkvT, f16* __restrict__ woT,
    f16* __restrict__ Q, f16* __restrict__ K, f16* __restrict__ VT,
    f16* __restrict__ ctx, float* __restrict__ out, unsigned* cnt) {
  __shared__ __attribute__((aligned(16))) char smem[65536];
  int bid = blockIdx.x;
  int wave = threadIdx.x >> 6, lane = threadIdx.x & 63;
  int lm = lane & 15, quad = lane >> 4;
  const unsigned NB = gridDim.x;

  // ================= P0: weight pack (blocks 0..63) =================
  if (bid < 64) {
    f16 (*lds)[72] = (f16(*)[72])smem;  // [64][72], 9.2 KB
    int dout0 = (bid & 15) * 64;        // 0..960
    int k0 = (bid >> 4) * 64;           // 0..192
    const float* src;
    f16* dst;
    int col0, drow;
    if (dout0 < 256)      { src = wq; dst = wqkvT; col0 = dout0;       drow = dout0; }
    else if (dout0 < 512) { src = wk; dst = wqkvT; col0 = dout0 - 256; drow = dout0; }
    else if (dout0 < 768) { src = wv; dst = wqkvT; col0 = dout0 - 512; drow = dout0; }
    else                  { src = wo; dst = woT;   col0 = dout0 - 768; drow = dout0 - 768; }

    int dl = threadIdx.x & 63, kl = threadIdx.x >> 6;
#pragma unroll
    for (int i = 0; i < 16; i++) {
      int kloc = i * 4 + kl;
      lds[kloc][dl] = (f16)src[(size_t)(k0 + kloc) * 256 + col0 + dl];
    }
    __syncthreads();
    int row_l = threadIdx.x >> 2, kq = threadIdx.x & 3;
    f16x8 v0, v1;
#pragma unroll
    for (int j = 0; j < 8; j++) v0[j] = lds[kq * 16 + j][row_l];
#pragma unroll
    for (int j = 0; j < 8; j++) v1[j] = lds[kq * 16 + 8 + j][row_l];
    f16* p = dst + (size_t)(drow + row_l) * 256 + k0 + kq * 16;
    *(f16x8*)p = v0;
    *(f16x8*)(p + 8) = v1;
  }
  gsync(&cnt[0], NB);

  // ================= P1: QKV GEMM (all 512 blocks) =================
  // block: m-tile = bid>>1 (64 rows), n-half = bid&1 -> tiles i0..i0+5 of 12.
  {
    f16 (*astage)[4][64][8] = (f16(*)[4][64][8])smem;            // 32 KB
    f16 (*bstage)[4][64][8] = (f16(*)[4][64][8])(smem + 32768);  // 32 KB
    f16 (*lds_t)[72] = (f16(*)[72])smem;  // ALIASES astage (dead after a[] load)
    int m0 = (bid >> 1) * 64;
    int i0 = (bid & 1) * 6, iend = i0 + 6;
    int bb = m0 >> 11, s0 = m0 & 2047;

    // coalesced x-tile load -> f16 frag-major astage
    {
      int row = threadIdx.x >> 2;          // 0..63
      int c0 = (threadIdx.x & 3) * 64;     // 4 threads cover one 1 KB row
      const float* xr = x + (size_t)(m0 + row) * 256 + c0;
#pragma unroll
      for (int i = 0; i < 8; i++) {
        f32x4 lo = *(const f32x4*)(xr + i * 8);
        f32x4 hh = *(const f32x4*)(xr + i * 8 + 4);
        f16x8 v;
#pragma unroll
        for (int j = 0; j < 4; j++) { v[j] = (f16)lo[j]; v[j + 4] = (f16)hh[j]; }
        int col = c0 + i * 8;
        *(f16x8*)&astage[col >> 5][row >> 4][((col >> 3) & 3) * 16 + (row & 15)][0] = v;
      }
    }
    __syncthreads();
    f16x8 a[8];
#pragma unroll
    for (int kk = 0; kk < 8; kk++) a[kk] = *(const f16x8*)&astage[kk][wave][lane][0];

    f16x8 breg[8];
    auto bload = [&](int n0) {
#pragma unroll
      for (int kk = 0; kk < 8; kk++)
        breg[kk] = *(const f16x8*)(wqkvT + (size_t)(n0 + wave * 16 + lm) * 256 + kk * 32 + quad * 8);
    };
    bload(i0 * 64);

    for (int i = i0; i < iend; i++) {
#pragma unroll
      for (int kk = 0; kk < 8; kk++)
        *(f16x8*)&bstage[kk][wave][lane][0] = breg[kk];
      __syncthreads();  // (A) bstage ready; all waves' a[] loads done
      if (i + 1 < iend) bload((i + 1) * 64);

      f32x4 acc[4] = {};
#pragma unroll
      for (int kk = 0; kk < 8; kk++)
#pragma unroll
        for (int nt = 0; nt < 4; nt++) {
          f16x8 b = *(const f16x8*)&bstage[kk][nt][lane][0];
          acc[nt] = __builtin_amdgcn_mfma_f32_16x16x32_f16(a[kk], b, acc[nt], 0, 0, 0);
        }

      int h = i & 3;
      if (i < 8) {
        // Q (i<4) or K: stage [s_local][dh] then coalesced f16x8 row stores
        float qsc = (i < 4) ? QSCALE : 1.0f;
#pragma unroll
        for (int nt = 0; nt < 4; nt++)
#pragma unroll
          for (int r = 0; r < 4; r++)
            lds_t[wave * 16 + quad * 4 + r][nt * 16 + lm] = (f16)(acc[nt][r] * qsc);
        __syncthreads();
        int rr = threadIdx.x >> 2, cc = threadIdx.x & 3;
        f16* dst = ((i < 4) ? Q : K) +
                   (((size_t)(bb * HH + h) * SS + s0 + rr) << 6) + cc * 16;
        *(f16x8*)dst = *(const f16x8*)&lds_t[rr][cc * 16];
        *(f16x8*)(dst + 8) = *(const f16x8*)&lds_t[rr][cc * 16 + 8];
      } else {
        // V: transpose tile -> V^T rows
#pragma unroll
        for (int nt = 0; nt < 4; nt++)
#pragma unroll
          for (int r = 0; r < 4; r++)
            lds_t[nt * 16 + lm][wave * 16 + quad * 4 + r] = (f16)acc[nt][r];
        __syncthreads();
        int rr = threadIdx.x >> 2, cc = threadIdx.x & 3;
        f16* vrow = VT + ((size_t)(bb * HH + h) * DHH + rr) * SS + s0;
        *(f16x8*)(vrow + cc * 16) = *(const f16x8*)&lds_t[rr][cc * 16];
        *(f16x8*)(vrow + cc * 16 + 8) = *(const f16x8*)&lds_t[rr][cc * 16 + 8];
      }
      __syncthreads();
    }
  }
  gsync(&cnt[1], NB);

  // ================= P2: flash attention (round-4 structure) =================
  // bid -> (qb 16, hd 4, b 8); 4 waves, wave owns 32 q-rows; NT=32 key tiles.
  {
    f16 (*kbuf)[8][64][8] = (f16(*)[8][64][8])smem;            // [2][8][64][8] 16 KB
    f16 (*vbuf)[8][64][8] = (f16(*)[8][64][8])(smem + 16384);  // 16 KB
    int qb = bid & 15, hd = (bid >> 4) & 3, b = bid >> 6;
    int w = wave;
    int l31 = lane & 31, hi = lane >> 5, hi8 = hi * 8;
    const f16* Qbh = Q + (size_t)(b * HH + hd) * SS * DHH;
    const f16* Kbh = K + (size_t)(b * HH + hd) * SS * DHH;
    const f16* Vbh = VT + (size_t)(b * HH + hd) * DHH * SS;
    int q0 = qb * 128 + w * 32;

    f16x8 tk0, tk1, tv0, tv1;
    auto stage_load = [&](int key0) {
      tk0 = *(const f16x8*)(Kbh + (size_t)(key0 + l31) * DHH + w * 16 + hi8);
      tk1 = *(const f16x8*)(Kbh + (size_t)(key0 + 32 + l31) * DHH + w * 16 + hi8);
      tv0 = *(const f16x8*)(Vbh + (size_t)l31 * SS + key0 + w * 16 + hi8);
      tv1 = *(const f16x8*)(Vbh + (size_t)(32 + l31) * SS + key0 + w * 16 + hi8);
    };
    auto stage_write = [&](int buf) {
      *(f16x8*)&kbuf[buf][w][lane][0] = tk0;
      *(f16x8*)&kbuf[buf][4 + w][lane][0] = tk1;
      *(f16x8*)&vbuf[buf][w][lane][0] = tv0;
      *(f16x8*)&vbuf[buf][4 + w][lane][0] = tv1;
    };

    f16x8 aq[4];
    {
      const f16* qrow = Qbh + (size_t)(q0 + l31) * DHH + hi8;
#pragma unroll
      for (int kp = 0; kp < 4; kp++) aq[kp] = *(const f16x8*)(qrow + kp * 16);
    }
    f16x8 vones;
#pragma unroll
    for (int j = 0; j < 8; j++) vones[j] = (f16)1.0f;
    f32x16 minit;
#pragma unroll
    for (int r = 0; r < 16; r++) minit[r] = -MOFF2;

    f32x16 accO0, accO1, accL;
#pragma unroll
    for (int r = 0; r < 16; r++) { accO0[r] = 0.f; accO1[r] = 0.f; accL[r] = 0.f; }

    stage_load(0);
    stage_write(0);
    stage_load(64);

    const int NT = SS / 64;  // 32 tiles
    for (int t = 0; t < NT; t++) {
      int cur = t & 1;
      __syncthreads();  // buf[cur] visible; prior reads of buf[1-cur] done

      if (t + 1 < NT) {
        stage_write(cur ^ 1);
        if (t + 2 < NT) stage_load((t + 2) * 64);
      }

      // S^T = K (Q*log2e/8)^T - 4*log2e : col=q (lane-local P rows)
      f32x16 accST[2];
#pragma unroll
      for (int kp = 0; kp < 4; kp++)
#pragma unroll
        for (int nt = 0; nt < 2; nt++) {
          f16x8 kf = *(const f16x8*)&kbuf[cur][nt * 4 + kp][lane][0];
          accST[nt] = __builtin_amdgcn_mfma_f32_32x32x16_f16(
              kf, aq[kp], kp == 0 ? minit : accST[nt], 0, 0, 0);
        }

      // P = exp2(S^T) in-register; repack via cvt_pkrtz + permlane32_swap
      f16x8 pa[4];
#pragma unroll
      for (int nt = 0; nt < 2; nt++) {
        u32 u[4][2];
#pragma unroll
        for (int bq = 0; bq < 4; bq++) {
          float p0 = __builtin_amdgcn_exp2f(accST[nt][4 * bq + 0]);
          float p1 = __builtin_amdgcn_exp2f(accST[nt][4 * bq + 1]);
          float p2 = __builtin_amdgcn_exp2f(accST[nt][4 * bq + 2]);
          float p3 = __builtin_amdgcn_exp2f(accST[nt][4 * bq + 3]);
          u[bq][0] = pkrtz(p0, p1);
          u[bq][1] = pkrtz(p2, p3);
        }
#pragma unroll
        for (int sl = 0; sl < 2; sl++) {
          auto r0 = __builtin_amdgcn_permlane32_swap(u[2 * sl][0], u[2 * sl + 1][0],
                                                     false, false);
          auto r1 = __builtin_amdgcn_permlane32_swap(u[2 * sl][1], u[2 * sl + 1][1],
                                                     false, false);
          u32x4 wv = {(u32)r0[0], (u32)r1[0], (u32)r0[1], (u32)r1[1]};
          pa[nt * 2 + sl] = __builtin_bit_cast(f16x8, wv);
        }
      }

      // O += P V ; l += P @ ones (accL/accO row maps identical)
#pragma unroll
      for (int ks = 0; ks < 4; ks++) {
        accL = __builtin_amdgcn_mfma_f32_32x32x16_f16(pa[ks], vones, accL, 0, 0, 0);
        f16x8 v0 = *(const f16x8*)&vbuf[cur][ks][lane][0];
        accO0 = __builtin_amdgcn_mfma_f32_32x32x16_f16(pa[ks], v0, accO0, 0, 0, 0);
        f16x8 v1 = *(const f16x8*)&vbuf[cur][4 + ks][lane][0];
        accO1 = __builtin_amdgcn_mfma_f32_32x32x16_f16(pa[ks], v1, accO1, 0, 0, 0);
      }
    }

    // epilogue: normalized ctx[b,s, hd*64+dh] f16
#pragma unroll
    for (int r = 0; r < 16; r++) {
      float rinv = __builtin_amdgcn_rcpf(accL[r]);
      int s = q0 + (r & 3) + 8 * (r >> 2) + 4 * hi;
      f16* dst = ctx + (size_t)(b * SS + s) * DD + hd * DHH + l31;
      dst[0]  = (f16)(accO0[r] * rinv);
      dst[32] = (f16)(accO1[r] * rinv);
    }
  }
  gsync(&cnt[2], NB);

  // ================= P3: out GEMM (all 512 blocks) =================
  // block: m-tile = bid>>1 (64 rows), n-half = bid&1 -> 2 n-iters.
  {
    f16 (*astage)[4][64][8] = (f16(*)[4][64][8])smem;            // 32 KB
    f16 (*bstage)[4][64][8] = (f16(*)[4][64][8])(smem + 32768);  // 32 KB
    int m0 = (bid >> 1) * 64;
    int nh = bid & 1;

    // coalesced ctx-tile load -> frag-major astage
    {
      int row = threadIdx.x >> 2;
      int c0 = (threadIdx.x & 3) * 64;
      const f16* cr = ctx + (size_t)(m0 + row) * 256 + c0;
#pragma unroll
      for (int i = 0; i < 8; i++) {
        f16x8 v = *(const f16x8*)(cr + i * 8);
        int col = c0 + i * 8;
        *(f16x8*)&astage[col >> 5][row >> 4][((col >> 3) & 3) * 16 + (row & 15)][0] = v;
      }
    }
    __syncthreads();
    f16x8 a[8];
#pragma unroll
    for (int kk = 0; kk < 8; kk++) a[kk] = *(const f16x8*)&astage[kk][wave][lane][0];

    f16x8 breg[8];
    auto bload = [&](int n0) {
#pragma unroll
      for (int kk = 0; kk < 8; kk++)
        breg[kk] = *(const f16x8*)(woT + (size_t)(n0 + wave * 16 + lm) * 256 + kk * 32 + quad * 8);
    };
    bload(nh * 128);

    for (int i = 0; i < 2; i++) {
      int n0 = nh * 128 + i * 64;
#pragma unroll
      for (int kk = 0; kk < 8; kk++)
        *(f16x8*)&bstage[kk][wave][lane][0] = breg[kk];
      __syncthreads();
      if (i + 1 < 2) bload(nh * 128 + 64);

      f32x4 acc[4] = {};
#pragma unroll
      for (int kk = 0; kk < 8; kk++)
#pragma unroll
        for (int nt = 0; nt < 4; nt++) {
          f16x8 bfr = *(const f16x8*)&bstage[kk][nt][lane][0];
          acc[nt] = __builtin_amdgcn_mfma_f32_16x16x32_f16(a[kk], bfr, acc[nt], 0, 0, 0);
        }
#pragma unroll
      for (int nt = 0; nt < 4; nt++) {
        int dout = n0 + nt * 16 + lm;
        float bias = bo[dout];
#pragma unroll
        for (int r = 0; r < 4; r++) {
          int t = m0 + wave * 16 + quad * 4 + r;
          out[(size_t)t * 256 + dout] = acc[nt][r] + bias;
        }
      }
      __syncthreads();
    }
  }
}

// ---------------------------------------------------------------------------
extern "C" void kernel_launch(void* const* d_in, const int* in_sizes, int n_in,
                              void* d_out, int out_size, void* d_ws, size_t ws_size,
                              hipStream_t stream) {
  const float* x  = (const float*)d_in[0];
  const float* wq = (const float*)d_in[1];
  const float* wk = (const float*)d_in[2];
  const float* wv = (const float*)d_in[3];
  const float* wo = (const float*)d_in[4];
  const float* bo = (const float*)d_in[5];
  float* out = (float*)d_out;

  char* ws = (char*)d_ws;
  const size_t SZ = 8388608;  // 16384*256*2 bytes
  f16* Qb    = (f16*)(ws);
  f16* Kb    = (f16*)(ws + SZ);
  f16* VTb   = (f16*)(ws + 2 * SZ);
  f16* ctxh  = (f16*)(ws + 3 * SZ);
  f16* wqkvT = (f16*)(ws + 4 * SZ);            // 768*256*2 = 393216
  f16* woT   = (f16*)(ws + 4 * SZ + 393216);   // 256*256*2 = 131072
  unsigned* cnt = (unsigned*)(ws + 4 * SZ + 393216 + 131072);  // 3 barrier counters

  hipMemsetAsync(cnt, 0, 3 * sizeof(unsigned), stream);
  hipLaunchKernelGGL(fused_kernel, dim3(512), dim3(256), 0, stream,
                     x, wq, wk, wv, wo, bo, wqkvT, woT, Qb, Kb, VTb, ctxh,
                     out, cnt);
}